// Round 9
// baseline (3370.028 us; speedup 1.0000x reference)
//
#include <hip/hip_runtime.h>
#include <hip/hip_fp16.h>

#define NN 100000
#define NE 3200000
#define NG 256
#define NF (NN * 64)
#define FEPS 1e-5f
#define BSH 8                       // 256 dst-nodes per bucket
#define NB ((NN + 255) >> 8)        // 391 buckets
#define CHA 8192                    // edges per block in pass A
#define NCB 8                       // src slices
#define SRCB 12500                  // src rows per slice (1.6 MB fp16 @64F)
#define DPW 32                      // dst nodes per wave
#define NW  (NN / DPW)              // 3125 waves for gather kernels
#define NCG (NCB * NW)              // 25000 (cb, dgroup) segments

static inline int ceil_div(int a, int b) { return (a + b - 1) / b; }

// ---------- pass A: coarse bucket partition of edges (unchanged) ----------

__global__ __launch_bounds__(256) void kA_hist(const int* __restrict__ dst,
                                               int* __restrict__ bh) {
    __shared__ int lh[NB];
    int t = threadIdx.x;
    for (int b = t; b < NB; b += 256) lh[b] = 0;
    __syncthreads();
    int e0 = blockIdx.x * CHA;
    int e1 = min(e0 + CHA, NE);
    for (int i = e0 + t; i < e1; i += 256) atomicAdd(&lh[dst[i] >> BSH], 1);
    __syncthreads();
    for (int b = t; b < NB; b += 256)
        if (lh[b]) atomicAdd(&bh[b], lh[b]);
}

__global__ __launch_bounds__(512) void kA_scan(const int* __restrict__ bh,
                                               int* __restrict__ bboff,
                                               int* __restrict__ bcur) {
    __shared__ int s[512];
    int t = threadIdx.x;
    int v = (t < NB) ? bh[t] : 0;
    s[t] = v;
    __syncthreads();
    for (int off = 1; off < 512; off <<= 1) {
        int add = (t >= off) ? s[t - off] : 0;
        __syncthreads();
        s[t] += add;
        __syncthreads();
    }
    if (t < NB) {
        int ex = s[t] - v;
        bboff[t] = ex;
        bcur[t] = ex;
    }
    if (t == 0) bboff[NB] = NE;
}

__global__ __launch_bounds__(256) void kA_fill(const int* __restrict__ src,
                                               const int* __restrict__ dst,
                                               int* __restrict__ bcur,
                                               int2* __restrict__ ebuf) {
    __shared__ int lh[NB];
    __shared__ int lbase[NB];
    __shared__ int lcur[NB];
    int t = threadIdx.x;
    for (int b = t; b < NB; b += 256) lh[b] = 0;
    __syncthreads();
    int e0 = blockIdx.x * CHA;
    int e1 = min(e0 + CHA, NE);
    for (int i = e0 + t; i < e1; i += 256) atomicAdd(&lh[dst[i] >> BSH], 1);
    __syncthreads();
    for (int b = t; b < NB; b += 256) {
        int c = lh[b];
        lbase[b] = c ? atomicAdd(&bcur[b], c) : 0;
        lcur[b] = 0;
    }
    __syncthreads();
    for (int i = e0 + t; i < e1; i += 256) {
        int d = dst[i];
        int s = src[i];
        int b = d >> BSH;
        int p = atomicAdd(&lcur[b], 1);
        ebuf[lbase[b] + p] = make_int2(s, d);
    }
}

// ---------- pass B: per-dst counts + per-(dgroup,cb) counts ----------

__global__ __launch_bounds__(256) void kB1(const int2* __restrict__ ebuf,
                                           const int* __restrict__ bboff,
                                           int* __restrict__ cnt,
                                           int* __restrict__ cgb) {
    __shared__ int lcnt[256];
    __shared__ int lcg[64];           // 8 dgroups x 8 cb per bucket
    int b = blockIdx.x, t = threadIdx.x;
    lcnt[t] = 0;
    if (t < 64) lcg[t] = 0;
    __syncthreads();
    int st = bboff[b], en = bboff[b + 1];
    for (int i = st + t; i < en; i += 256) {
        int2 e = ebuf[i];
        int dl8 = e.y & 255;
        int cb = e.x / SRCB;
        atomicAdd(&lcnt[dl8], 1);
        atomicAdd(&lcg[(dl8 >> 5) * 8 + cb], 1);
    }
    __syncthreads();
    int node = (b << 8) + t;
    if (node < NN) cnt[node] = lcnt[t];
    if (t < 64) {
        int dgl = t >> 3, cb = t & 7;
        int dg = (b << 3) + dgl;      // global dgroup (32 dst each)
        if (dg < NW) cgb[cb * NW + dg] = lcg[t];
    }
}

// ---- scan of cgb[NCG] -> rowptrG (exclusive), hierarchical ----

__global__ __launch_bounds__(256) void kS1(const int* __restrict__ cgb,
                                           int* __restrict__ bs2) {
    __shared__ int s[256];
    int t = threadIdx.x;
    int i = blockIdx.x * 256 + t;
    s[t] = (i < NCG) ? cgb[i] : 0;
    __syncthreads();
    for (int off = 128; off > 0; off >>= 1) {
        if (t < off) s[t] += s[t + off];
        __syncthreads();
    }
    if (t == 0) bs2[blockIdx.x] = s[0];
}

__global__ __launch_bounds__(128) void kS2(int* __restrict__ bs2, int nb) {
    __shared__ int s[128];
    int t = threadIdx.x;
    int v = (t < nb) ? bs2[t] : 0;
    s[t] = v;
    __syncthreads();
    for (int off = 1; off < 128; off <<= 1) {
        int add = (t >= off) ? s[t - off] : 0;
        __syncthreads();
        s[t] += add;
        __syncthreads();
    }
    if (t < nb) bs2[t] = s[t] - v;    // exclusive
}

__global__ __launch_bounds__(256) void kS3(const int* __restrict__ cgb,
                                           const int* __restrict__ bs2,
                                           int* __restrict__ rowptrG) {
    __shared__ int s[256];
    int t = threadIdx.x;
    int i = blockIdx.x * 256 + t;
    int v = (i < NCG) ? cgb[i] : 0;
    s[t] = v;
    __syncthreads();
    for (int off = 1; off < 256; off <<= 1) {
        int add = (t >= off) ? s[t - off] : 0;
        __syncthreads();
        s[t] += add;
        __syncthreads();
    }
    if (i < NCG) rowptrG[i] = s[t] - v + bs2[blockIdx.x];
    if (blockIdx.x == 0 && t == 0) rowptrG[NCG] = NE;
}

// fill csr grouped by (cb, dgroup); record = src | (dst&31)<<17
__global__ __launch_bounds__(256) void kB2(const int2* __restrict__ ebuf,
                                           const int* __restrict__ bboff,
                                           const int* __restrict__ rowptrG,
                                           int* __restrict__ csr) {
    __shared__ int cur[64];
    int b = blockIdx.x, t = threadIdx.x;
    if (t < 64) {
        int dgl = t >> 3, cb = t & 7;
        int dg = (b << 3) + dgl;
        cur[t] = (dg < NW) ? rowptrG[cb * NW + dg] : 0;
    }
    __syncthreads();
    int st = bboff[b], en = bboff[b + 1];
    for (int i = st + t; i < en; i += 256) {
        int2 e = ebuf[i];
        int cb = e.x / SRCB;
        int dl8 = e.y & 255;
        int pos = atomicAdd(&cur[(dl8 >> 5) * 8 + cb], 1);
        csr[pos] = e.x | ((dl8 & 31) << 17);
    }
}

// ---------- misc prep ----------

__global__ __launch_bounds__(256) void k_dinv_xs(const int* __restrict__ cnt,
                                                 const float* __restrict__ x,
                                                 float* __restrict__ dinv,
                                                 __half* __restrict__ xs) {
    int i = blockIdx.x * 256 + threadIdx.x;
    if (i >= NN) return;
    float di = rsqrtf((float)cnt[i] + 1.0f);
    dinv[i] = di;
#pragma unroll
    for (int f = 0; f < 8; ++f) xs[i * 8 + f] = __float2half(x[i * 8 + f] * di);
}

__global__ __launch_bounds__(256) void k_cnts(const int* __restrict__ batch,
                                              float* __restrict__ cnts) {
    int c = blockIdx.x * 256 + threadIdx.x;
    int n0 = c * 64;
    if (n0 >= NN) return;
    int n1 = min(n0 + 64, NN);
    int gcur = batch[n0];
    float cf = 0.f;
    for (int n = n0; n < n1; ++n) {
        int gg = batch[n];
        if (gg != gcur) {
            atomicAdd(&cnts[gcur], cf);
            cf = 0.f;
            gcur = gg;
        }
        cf += 1.f;
    }
    atomicAdd(&cnts[gcur], cf);
}

// ---------- layer 1: sliced gather of xs (8-wide) + 8->64 + BN + ReLU -------
// Wave owns 32 dst; LDS acc 32x8 fp32; slices looped in-kernel.

__global__ __launch_bounds__(256) void k_gslice8(const __half2* __restrict__ xs2,
                                                 const int* __restrict__ rowptrG,
                                                 const float* __restrict__ dinv,
                                                 const int* __restrict__ csr,
                                                 const float* __restrict__ W,
                                                 const float* __restrict__ bb,
                                                 const float* __restrict__ g,
                                                 const float* __restrict__ be,
                                                 const float* __restrict__ rm,
                                                 const float* __restrict__ rv,
                                                 __half* __restrict__ out) {
    __shared__ float accW[4 * DPW * 8];    // 4 KB
    int tid = threadIdx.x;
    int wid = (blockIdx.x * 256 + tid) >> 6;
    int lane = tid & 63;
    int wslot = tid >> 6;
    if (wid >= NW) return;
    int d0 = wid * DPW;
    float* acc = &accW[wslot * DPW * 8];
    int e4 = lane >> 2, q4 = lane & 3;
    // init with self (xs pre-scaled); 64 lanes cover 16 (dl,q) pairs x2 iters
#pragma unroll
    for (int i = 0; i < 2; ++i) {
        int dl = (lane >> 2) + i * 16;
        float2 f = __half22float2(xs2[(d0 + dl) * 4 + q4]);
        acc[dl * 8 + 2 * q4] = f.x;
        acc[dl * 8 + 2 * q4 + 1] = f.y;
    }
    for (int cb = 0; cb < NCB; ++cb) {
        int st = rowptrG[cb * NW + wid];
        int en = rowptrG[cb * NW + wid + 1];
        int n = en - st;
        int k = 0;
        while (k < n) {
            int rem = n - k;
            int chunk = rem < 64 ? rem : 64;
            int ew = (lane < chunk) ? csr[st + k + lane] : 0;
            for (int j = 0; j < chunk; j += 16) {   // 16 edges per round
                int kk = j + e4;
                int w = __shfl(ew, kk & 63, 64);
                if (kk < chunk) {
                    int s = w & 0x1FFFF;
                    int dl = w >> 17;
                    float2 f = __half22float2(xs2[s * 4 + q4]);
                    atomicAdd(&acc[dl * 8 + 2 * q4], f.x);
                    atomicAdd(&acc[dl * 8 + 2 * q4 + 1], f.y);
                }
            }
            k += chunk;
        }
    }
    // transform 8->64 (+BN+ReLU), W read via L1 (shared by all waves)
    float scale = g[lane] * rsqrtf(rv[lane] + FEPS);
    float shift = be[lane] + (bb[lane] - rm[lane]) * scale;
    for (int g4 = 0; g4 < 4; ++g4) {
        int dbase = g4 * 8;
        float oo[8];
#pragma unroll
        for (int d = 0; d < 8; ++d) oo[d] = 0.f;
#pragma unroll
        for (int f = 0; f < 8; ++f) {
            float wf = W[f * 64 + lane];
#pragma unroll
            for (int d = 0; d < 8; ++d)
                oo[d] = fmaf(acc[(dbase + d) * 8 + f], wf, oo[d]);  // LDS bcast
        }
#pragma unroll
        for (int d = 0; d < 8; ++d) {
            int dd = d0 + dbase + d;
            float di = dinv[dd];
            float o = fmaxf(fmaf(oo[d] * di, scale, shift), 0.f);
            out[dd * 64 + lane] = __float2half(o * di);   // pre-scaled
        }
    }
}

// ---------- layers 2/3: sliced gather (64-wide) + 64->64 + BN + ReLU --------
// Wave owns 32 dst; LDS acc 32x64 fp32 (8 KB/wave); slices looped in-kernel.

template <bool POOL>
__global__ __launch_bounds__(256) void k_gslice(const __half2* __restrict__ Hin2,
                                                const int* __restrict__ rowptrG,
                                                const float* __restrict__ dinv,
                                                const int* __restrict__ csr,
                                                const float* __restrict__ W,
                                                const float* __restrict__ bb,
                                                const float* __restrict__ g,
                                                const float* __restrict__ be,
                                                const float* __restrict__ rm,
                                                const float* __restrict__ rv,
                                                const int* __restrict__ batch,
                                                __half* __restrict__ out,
                                                float* __restrict__ sums) {
    __shared__ float accW[4 * DPW * 64];   // 32 KB
    int tid = threadIdx.x;
    int wid = (blockIdx.x * 256 + tid) >> 6;
    int lane = tid & 63;
    int wslot = tid >> 6;
    if (wid >= NW) return;
    int d0 = wid * DPW;
    int p = lane >> 5, q = lane & 31;
    float* acc = &accW[wslot * DPW * 64];
    // init with self (Hin pre-scaled): p selects dl half
#pragma unroll
    for (int i = 0; i < 16; ++i) {
        int dl = p * 16 + i;
        float2 f = __half22float2(Hin2[(d0 + dl) * 32 + q]);
        acc[dl * 64 + 2 * q] = f.x;
        acc[dl * 64 + 2 * q + 1] = f.y;
    }
    for (int cb = 0; cb < NCB; ++cb) {
        int st = rowptrG[cb * NW + wid];
        int en = rowptrG[cb * NW + wid + 1];
        int n = en - st;
        int k = 0;
        while (k < n) {
            int rem = n - k;
            int chunk = rem < 64 ? rem : 64;
            int ew = (lane < chunk) ? csr[st + k + lane] : 0;
            int j = 0;
            for (; j + 16 <= chunk; j += 16) {   // 8 pairs = 16 edges
                int w0 = __shfl(ew, j + 0 + p, 64);
                int w1 = __shfl(ew, j + 2 + p, 64);
                int w2 = __shfl(ew, j + 4 + p, 64);
                int w3 = __shfl(ew, j + 6 + p, 64);
                int w4 = __shfl(ew, j + 8 + p, 64);
                int w5 = __shfl(ew, j + 10 + p, 64);
                int w6 = __shfl(ew, j + 12 + p, 64);
                int w7 = __shfl(ew, j + 14 + p, 64);
                float2 f0 = __half22float2(Hin2[(w0 & 0x1FFFF) * 32 + q]);
                float2 f1 = __half22float2(Hin2[(w1 & 0x1FFFF) * 32 + q]);
                float2 f2 = __half22float2(Hin2[(w2 & 0x1FFFF) * 32 + q]);
                float2 f3 = __half22float2(Hin2[(w3 & 0x1FFFF) * 32 + q]);
                float2 f4 = __half22float2(Hin2[(w4 & 0x1FFFF) * 32 + q]);
                float2 f5 = __half22float2(Hin2[(w5 & 0x1FFFF) * 32 + q]);
                float2 f6 = __half22float2(Hin2[(w6 & 0x1FFFF) * 32 + q]);
                float2 f7 = __half22float2(Hin2[(w7 & 0x1FFFF) * 32 + q]);
                atomicAdd(&acc[(w0 >> 17) * 64 + 2 * q], f0.x);
                atomicAdd(&acc[(w0 >> 17) * 64 + 2 * q + 1], f0.y);
                atomicAdd(&acc[(w1 >> 17) * 64 + 2 * q], f1.x);
                atomicAdd(&acc[(w1 >> 17) * 64 + 2 * q + 1], f1.y);
                atomicAdd(&acc[(w2 >> 17) * 64 + 2 * q], f2.x);
                atomicAdd(&acc[(w2 >> 17) * 64 + 2 * q + 1], f2.y);
                atomicAdd(&acc[(w3 >> 17) * 64 + 2 * q], f3.x);
                atomicAdd(&acc[(w3 >> 17) * 64 + 2 * q + 1], f3.y);
                atomicAdd(&acc[(w4 >> 17) * 64 + 2 * q], f4.x);
                atomicAdd(&acc[(w4 >> 17) * 64 + 2 * q + 1], f4.y);
                atomicAdd(&acc[(w5 >> 17) * 64 + 2 * q], f5.x);
                atomicAdd(&acc[(w5 >> 17) * 64 + 2 * q + 1], f5.y);
                atomicAdd(&acc[(w6 >> 17) * 64 + 2 * q], f6.x);
                atomicAdd(&acc[(w6 >> 17) * 64 + 2 * q + 1], f6.y);
                atomicAdd(&acc[(w7 >> 17) * 64 + 2 * q], f7.x);
                atomicAdd(&acc[(w7 >> 17) * 64 + 2 * q + 1], f7.y);
            }
            for (; j + 2 <= chunk; j += 2) {
                int w = __shfl(ew, j + p, 64);
                float2 f = __half22float2(Hin2[(w & 0x1FFFF) * 32 + q]);
                atomicAdd(&acc[(w >> 17) * 64 + 2 * q], f.x);
                atomicAdd(&acc[(w >> 17) * 64 + 2 * q + 1], f.y);
            }
            if (j < chunk) {                 // odd leftover: p==0 half only
                int w = __shfl(ew, j, 64);
                if (p == 0) {
                    float2 f = __half22float2(Hin2[(w & 0x1FFFF) * 32 + q]);
                    atomicAdd(&acc[(w >> 17) * 64 + 2 * q], f.x);
                    atomicAdd(&acc[(w >> 17) * 64 + 2 * q + 1], f.y);
                }
            }
            k += chunk;
        }
    }
    // transform 64->64 (+BN+ReLU), f-major with 8-dst register blocking
    float scale = g[lane] * rsqrtf(rv[lane] + FEPS);
    float shift = be[lane] + (bb[lane] - rm[lane]) * scale;
    for (int g4 = 0; g4 < 4; ++g4) {
        int dbase = g4 * 8;
        float pf[8], oo[8];
#pragma unroll
        for (int d = 0; d < 8; ++d) {
            pf[d] = acc[(dbase + d) * 64 + lane] * dinv[d0 + dbase + d];
            oo[d] = 0.f;
        }
#pragma unroll
        for (int f = 0; f < 64; ++f) {
            float wf = W[f * 64 + lane];
#pragma unroll
            for (int d = 0; d < 8; ++d)
                oo[d] = fmaf(__shfl(pf[d], f, 64), wf, oo[d]);
        }
#pragma unroll
        for (int d = 0; d < 8; ++d) {
            int dd = d0 + dbase + d;
            float o = fmaxf(fmaf(oo[d], scale, shift), 0.f);
            if (POOL) {
                atomicAdd(&sums[batch[dd] * 64 + lane], o);
            } else {
                out[dd * 64 + lane] = __float2half(o * dinv[dd]);
            }
        }
    }
}

// ---------- head ----------

__global__ __launch_bounds__(256) void k_head(const float* __restrict__ sums,
                                              const float* __restrict__ cnts,
                                              const float* __restrict__ Wr1,
                                              const float* __restrict__ br1,
                                              const float* __restrict__ Wr2,
                                              const float* __restrict__ br2,
                                              float* __restrict__ out) {
    int wave = (blockIdx.x * 256 + threadIdx.x) >> 6;
    int lane = threadIdx.x & 63;
    if (wave >= NG) return;
    float c = fmaxf(cnts[wave], 1.0f);
    float pooled = sums[wave * 64 + lane] / c;
    float acc = 0.f;
#pragma unroll
    for (int k = 0; k < 64; ++k)
        acc = fmaf(__shfl(pooled, k, 64), Wr1[k * 64 + lane], acc);
    float hid = fmaxf(acc + br1[lane], 0.f);
    float o0 = hid * Wr2[lane * 2 + 0];
    float o1 = hid * Wr2[lane * 2 + 1];
#pragma unroll
    for (int off = 32; off > 0; off >>= 1) {
        o0 += __shfl_xor(o0, off, 64);
        o1 += __shfl_xor(o1, off, 64);
    }
    if (lane == 0) {
        out[wave * 2 + 0] = o0 + br2[0];
        out[wave * 2 + 1] = o1 + br2[1];
    }
}

extern "C" void kernel_launch(void* const* d_in, const int* in_sizes, int n_in,
                              void* d_out, int out_size, void* d_ws, size_t ws_size,
                              hipStream_t stream) {
    const float* x   = (const float*)d_in[0];
    const int*   ei  = (const int*)d_in[1];     // [2, E]: row0=src, row1=dst
    const int*   bat = (const int*)d_in[2];
    const float* W1  = (const float*)d_in[3];
    const float* b1  = (const float*)d_in[4];
    const float* g1  = (const float*)d_in[5];
    const float* be1 = (const float*)d_in[6];
    const float* rm1 = (const float*)d_in[7];
    const float* rv1 = (const float*)d_in[8];
    const float* W2  = (const float*)d_in[9];
    const float* b2  = (const float*)d_in[10];
    const float* g2  = (const float*)d_in[11];
    const float* be2 = (const float*)d_in[12];
    const float* rm2 = (const float*)d_in[13];
    const float* rv2 = (const float*)d_in[14];
    const float* W3  = (const float*)d_in[15];
    const float* b3  = (const float*)d_in[16];
    const float* g3  = (const float*)d_in[17];
    const float* be3 = (const float*)d_in[18];
    const float* rm3 = (const float*)d_in[19];
    const float* rv3 = (const float*)d_in[20];
    const float* Wr1 = (const float*)d_in[21];
    const float* br1 = (const float*)d_in[22];
    const float* Wr2 = (const float*)d_in[23];
    const float* br2 = (const float*)d_in[24];
    float* out = (float*)d_out;

    // workspace layout (4-byte words) — total ~41 MB (R1 proved ws >= ~90 MB)
    int*    cnt     = (int*)d_ws;                  // NN
    int*    rowptrG = cnt + NN;                    // NCG + 1
    int*    cgb     = rowptrG + NCG + 1;           // NCG
    int*    bs2     = cgb + NCG;                   // 128
    int*    bh      = bs2 + 128;                   // NB
    int*    bboff   = bh + NB;                     // NB+1
    int*    bcur    = bboff + NB + 1;              // NB
    float*  dinv    = (float*)(bcur + NB);         // NN
    int*    csr     = (int*)(dinv + NN);           // NE
    __half* xs      = (__half*)(csr + NE);         // NN*8 halves
    float*  sums    = (float*)(xs + NN * 8);       // NG*64
    float*  cnts    = sums + NG * 64;              // NG
    __half* A       = (__half*)(cnts + NG);        // NF halves
    __half* B       = A + NF;                      // NF halves
    int2*   ebuf    = (int2*)A;                    // NE int2 == A+B words; dead
                                                   //  after kB2, before layer 1

    const int* srcI = ei;
    const int* dstI = ei + NE;

    const int gA = ceil_div(NE, CHA);        // 391
    const int gN = ceil_div(NN, 256);        // 391
    const int gS = ceil_div(NCG, 256);       // 98
    const int gG = ceil_div(NW * 64, 256);   // 782 blocks (4 waves each)

    hipMemsetAsync(bh, 0, NB * sizeof(int), stream);
    hipMemsetAsync(sums, 0, (NG * 64 + NG) * sizeof(float), stream);

    // CSR build: bucket partition -> (cb, dgroup)-major packed CSR
    kA_hist<<<gA, 256, 0, stream>>>(dstI, bh);
    kA_scan<<<1, 512, 0, stream>>>(bh, bboff, bcur);
    kA_fill<<<gA, 256, 0, stream>>>(srcI, dstI, bcur, ebuf);
    kB1<<<NB, 256, 0, stream>>>(ebuf, bboff, cnt, cgb);
    k_dinv_xs<<<gN, 256, 0, stream>>>(cnt, x, dinv, xs);
    k_cnts<<<ceil_div(ceil_div(NN, 64), 256), 256, 0, stream>>>(bat, cnts);
    kS1<<<gS, 256, 0, stream>>>(cgb, bs2);
    kS2<<<1, 128, 0, stream>>>(bs2, gS);
    kS3<<<gS, 256, 0, stream>>>(cgb, bs2, rowptrG);
    kB2<<<NB, 256, 0, stream>>>(ebuf, bboff, rowptrG, csr);

    // layers: sliced gather with LDS accumulators, fused transform+BN+ReLU
    k_gslice8<<<gG, 256, 0, stream>>>((const __half2*)xs, rowptrG, dinv, csr,
                                      W1, b1, g1, be1, rm1, rv1, A);
    k_gslice<false><<<gG, 256, 0, stream>>>((const __half2*)A, rowptrG, dinv, csr,
                                            W2, b2, g2, be2, rm2, rv2,
                                            bat, B, nullptr);
    k_gslice<true><<<gG, 256, 0, stream>>>((const __half2*)B, rowptrG, dinv, csr,
                                           W3, b3, g3, be3, rm3, rv3,
                                           bat, nullptr, sums);

    k_head<<<ceil_div(NG * 64, 256), 256, 0, stream>>>(sums, cnts, Wr1, br1, Wr2, br2, out);
}

// Round 10
// 754.703 us; speedup vs baseline: 4.4654x; 4.4654x over previous
//
#include <hip/hip_runtime.h>
#include <hip/hip_fp16.h>

#define NN 100000
#define NE 3200000
#define NG 256
#define NF (NN * 64)
#define FEPS 1e-5f
#define BSH 8                       // 256 dst-nodes per bucket
#define NB ((NN + 255) >> 8)        // 391 buckets
#define CHA 8192                    // edges per block in pass A

static inline int ceil_div(int a, int b) { return (a + b - 1) / b; }

// ---------- pass A: coarse bucket partition of edges ----------

__global__ __launch_bounds__(256) void kA_hist(const int* __restrict__ dst,
                                               int* __restrict__ bh) {
    __shared__ int lh[NB];
    int t = threadIdx.x;
    for (int b = t; b < NB; b += 256) lh[b] = 0;
    __syncthreads();
    int e0 = blockIdx.x * CHA;
    int e1 = min(e0 + CHA, NE);
    for (int i = e0 + t; i < e1; i += 256) atomicAdd(&lh[dst[i] >> BSH], 1);
    __syncthreads();
    for (int b = t; b < NB; b += 256)
        if (lh[b]) atomicAdd(&bh[b], lh[b]);
}

__global__ __launch_bounds__(512) void kA_scan(const int* __restrict__ bh,
                                               int* __restrict__ bboff,
                                               int* __restrict__ bcur) {
    __shared__ int s[512];
    int t = threadIdx.x;
    int v = (t < NB) ? bh[t] : 0;
    s[t] = v;
    __syncthreads();
    for (int off = 1; off < 512; off <<= 1) {
        int add = (t >= off) ? s[t - off] : 0;
        __syncthreads();
        s[t] += add;
        __syncthreads();
    }
    if (t < NB) {
        int ex = s[t] - v;
        bboff[t] = ex;
        bcur[t] = ex;
    }
    if (t == 0) bboff[NB] = NE;
}

__global__ __launch_bounds__(256) void kA_fill(const int* __restrict__ src,
                                               const int* __restrict__ dst,
                                               int* __restrict__ bcur,
                                               int2* __restrict__ ebuf) {
    __shared__ int lh[NB];
    __shared__ int lbase[NB];
    __shared__ int lcur[NB];
    int t = threadIdx.x;
    for (int b = t; b < NB; b += 256) lh[b] = 0;
    __syncthreads();
    int e0 = blockIdx.x * CHA;
    int e1 = min(e0 + CHA, NE);
    for (int i = e0 + t; i < e1; i += 256) atomicAdd(&lh[dst[i] >> BSH], 1);
    __syncthreads();
    for (int b = t; b < NB; b += 256) {
        int c = lh[b];
        lbase[b] = c ? atomicAdd(&bcur[b], c) : 0;
        lcur[b] = 0;
    }
    __syncthreads();
    for (int i = e0 + t; i < e1; i += 256) {
        int d = dst[i];
        int s = src[i];
        int b = d >> BSH;
        int p = atomicAdd(&lcur[b], 1);
        ebuf[lbase[b] + p] = make_int2(s, d);
    }
}

// ---------- pass B: per-bucket node hist + CSR fill ----------

__global__ __launch_bounds__(256) void kB_hist(const int2* __restrict__ ebuf,
                                               const int* __restrict__ bboff,
                                               int* __restrict__ cnt) {
    __shared__ int lc[256];
    int b = blockIdx.x;
    int t = threadIdx.x;
    lc[t] = 0;
    __syncthreads();
    int st = bboff[b], en = bboff[b + 1];
    for (int i = st + t; i < en; i += 256) atomicAdd(&lc[ebuf[i].y & 255], 1);
    __syncthreads();
    int node = (b << BSH) + t;
    if (node < NN) cnt[node] = lc[t];
}

__global__ __launch_bounds__(256) void k_dinv_xs(const int* __restrict__ cnt,
                                                 const float* __restrict__ x,
                                                 float* __restrict__ dinv,
                                                 __half* __restrict__ xs) {
    int i = blockIdx.x * 256 + threadIdx.x;
    if (i >= NN) return;
    float di = rsqrtf((float)cnt[i] + 1.0f);
    dinv[i] = di;
#pragma unroll
    for (int f = 0; f < 8; ++f) xs[i * 8 + f] = __float2half(x[i * 8 + f] * di);
}

__global__ __launch_bounds__(256) void k_scan1(const int* __restrict__ cnt,
                                               int* __restrict__ bsum) {
    __shared__ int s[256];
    int t = threadIdx.x;
    int i = blockIdx.x * 256 + t;
    s[t] = (i < NN) ? cnt[i] : 0;
    __syncthreads();
    for (int off = 128; off > 0; off >>= 1) {
        if (t < off) s[t] += s[t + off];
        __syncthreads();
    }
    if (t == 0) bsum[blockIdx.x] = s[0];
}

__global__ __launch_bounds__(512) void k_scan2(int* __restrict__ bsum, int nb) {
    __shared__ int s[512];
    int t = threadIdx.x;
    int v = (t < nb) ? bsum[t] : 0;
    s[t] = v;
    __syncthreads();
    for (int off = 1; off < 512; off <<= 1) {
        int add = (t >= off) ? s[t - off] : 0;
        __syncthreads();
        s[t] += add;
        __syncthreads();
    }
    if (t < nb) bsum[t] = s[t] - v;   // exclusive
}

__global__ __launch_bounds__(256) void k_scan3(const int* __restrict__ cnt,
                                               const int* __restrict__ bsum,
                                               int* __restrict__ rowptr) {
    __shared__ int s[256];
    int t = threadIdx.x;
    int i = blockIdx.x * 256 + t;
    int v = (i < NN) ? cnt[i] : 0;
    s[t] = v;
    __syncthreads();
    for (int off = 1; off < 256; off <<= 1) {
        int add = (t >= off) ? s[t - off] : 0;
        __syncthreads();
        s[t] += add;
        __syncthreads();
    }
    if (i < NN) rowptr[i] = s[t] - v + bsum[blockIdx.x];
}

__global__ __launch_bounds__(256) void kB_fill(const int2* __restrict__ ebuf,
                                               const int* __restrict__ bboff,
                                               const int* __restrict__ rowptr,
                                               int* __restrict__ csr) {
    __shared__ int rp[256];
    __shared__ int lc[256];
    int b = blockIdx.x;
    int t = threadIdx.x;
    int node = (b << BSH) + t;
    rp[t] = (node < NN) ? rowptr[node] : 0;
    lc[t] = 0;
    __syncthreads();
    int st = bboff[b], en = bboff[b + 1];
    for (int i = st + t; i < en; i += 256) {
        int2 e = ebuf[i];
        int dl = e.y & 255;
        int p = atomicAdd(&lc[dl], 1);
        csr[rp[dl] + p] = e.x;
    }
}

__global__ __launch_bounds__(256) void k_cnts(const int* __restrict__ batch,
                                              float* __restrict__ cnts) {
    int c = blockIdx.x * 256 + threadIdx.x;
    int n0 = c * 64;
    if (n0 >= NN) return;
    int n1 = min(n0 + 64, NN);
    int gcur = batch[n0];
    float cf = 0.f;
    for (int n = n0; n < n1; ++n) {
        int gg = batch[n];
        if (gg != gcur) {
            atomicAdd(&cnts[gcur], cf);
            cf = 0.f;
            gcur = gg;
        }
        cf += 1.f;
    }
    atomicAdd(&cnts[gcur], cf);
}

// ---------- layer 1: gather xs + 8->64 + BN + ReLU, output fb-split ----------
// Output layout: Afb[(fb*NN + node)*16 + (f&15)], fb = f>>4, fp16 pre-scaled.

__global__ __launch_bounds__(256) void k_gxf8(const __half2* __restrict__ xs2,
                                              const int* __restrict__ rowptr,
                                              const int* __restrict__ cnt,
                                              const float* __restrict__ dinv,
                                              const int* __restrict__ csr,
                                              const float* __restrict__ W,
                                              const float* __restrict__ b,
                                              const float* __restrict__ g,
                                              const float* __restrict__ be,
                                              const float* __restrict__ rm,
                                              const float* __restrict__ rv,
                                              __half* __restrict__ Afb) {
    __shared__ float Ws[512];
    int tid = threadIdx.x;
    for (int i = tid; i < 512; i += 256) Ws[i] = W[i];
    __syncthreads();
    int wave = (blockIdx.x * 256 + tid) >> 6;
    int lane = tid & 63;
    if (wave >= NN) return;
    int es = lane >> 2, q4 = lane & 3;
    int st = rowptr[wave], n = cnt[wave];
    float ax = 0.f, ay = 0.f;
    for (int k0 = 0; k0 < n; k0 += 16) {
        int kk = k0 + es;
        if (kk < n) {
            float2 f = __half22float2(xs2[csr[st + kk] * 4 + q4]);
            ax += f.x; ay += f.y;
        }
    }
    ax += __shfl_xor(ax, 4, 64);  ay += __shfl_xor(ay, 4, 64);
    ax += __shfl_xor(ax, 8, 64);  ay += __shfl_xor(ay, 8, 64);
    ax += __shfl_xor(ax, 16, 64); ay += __shfl_xor(ay, 16, 64);
    ax += __shfl_xor(ax, 32, 64); ay += __shfl_xor(ay, 32, 64);
    float di = dinv[wave];
    float2 s2 = __half22float2(xs2[wave * 4 + q4]);
    float pfx = (ax + s2.x) * di;
    float pfy = (ay + s2.y) * di;
    float scale = g[lane] * rsqrtf(rv[lane] + FEPS);
    float shift = be[lane] + (b[lane] - rm[lane]) * scale;
    float o = 0.f;
#pragma unroll
    for (int qq = 0; qq < 4; ++qq) {
        float vx = __shfl(pfx, qq, 64);
        float vy = __shfl(pfy, qq, 64);
        o = fmaf(vx, Ws[(2 * qq) * 64 + lane], o);
        o = fmaf(vy, Ws[(2 * qq + 1) * 64 + lane], o);
    }
    o = fmaxf(fmaf(o, scale, shift), 0.f);
    int fb = lane >> 4;
    Afb[(fb * NN + wave) * 16 + (lane & 15)] = __float2half(o * di);  // pre-scaled
}

// ---------- layer 2: feature-split partial-aggregate pass (16 features) -----
// Afb/P pointers already offset to slab fb. Wave per dst; lane = e3*8 + q3.
__global__ __launch_bounds__(256) void k_pass(const __half2* __restrict__ Afb,
                                              const int* __restrict__ rowptr,
                                              const int* __restrict__ cnt,
                                              const int* __restrict__ csr,
                                              float2* __restrict__ P) {
    int tid = threadIdx.x;
    int wave = (blockIdx.x * 256 + tid) >> 6;
    int lane = tid & 63;
    if (wave >= NN) return;
    int e3 = lane >> 3, q3 = lane & 7;
    int st = rowptr[wave], n = cnt[wave];
    float ax = 0.f, ay = 0.f;
    int k = 0;
    while (k < n) {
        int rem = n - k;
        int chunk = rem < 64 ? rem : 64;
        int ew = (lane < chunk) ? csr[st + k + lane] : 0;
        if (chunk == 64) {
#pragma unroll
            for (int j = 0; j < 8; ++j) {
                int s = __shfl(ew, j * 8 + e3, 64);
                float2 f = __half22float2(Afb[s * 8 + q3]);
                ax += f.x; ay += f.y;
            }
        } else {
            for (int j = 0; j * 8 < chunk; ++j) {
                int s = __shfl(ew, j * 8 + e3, 64);
                if (j * 8 + e3 < chunk) {
                    float2 f = __half22float2(Afb[s * 8 + q3]);
                    ax += f.x; ay += f.y;
                }
            }
        }
        k += chunk;
    }
    // reduce over e3 (lane bits 3..5)
    ax += __shfl_xor(ax, 8, 64);  ay += __shfl_xor(ay, 8, 64);
    ax += __shfl_xor(ax, 16, 64); ay += __shfl_xor(ay, 16, 64);
    ax += __shfl_xor(ax, 32, 64); ay += __shfl_xor(ay, 32, 64);
    if (e3 == 0) P[wave * 8 + q3] = make_float2(ax, ay);
}

// ---------- layer 2 transform: P + self -> matvec -> BN -> ReLU -------------
// Reads P[4][NN][16] fp32 + Afb self; writes row-major B (pre-scaled fp16).
__global__ __launch_bounds__(256) void k_xf2(const float* __restrict__ Pf,
                                             const __half* __restrict__ Ah,
                                             const float* __restrict__ dinv,
                                             const float* __restrict__ W,
                                             const float* __restrict__ bb,
                                             const float* __restrict__ g,
                                             const float* __restrict__ be,
                                             const float* __restrict__ rm,
                                             const float* __restrict__ rv,
                                             __half* __restrict__ outRow) {
    __shared__ float Ws[4096];
    int tid = threadIdx.x;
    for (int i = tid; i < 4096; i += 256) Ws[i] = W[i];
    __syncthreads();
    int wave = (blockIdx.x * 256 + tid) >> 6;
    int lane = tid & 63;
    if (wave >= NN) return;
    int fb = lane >> 4, fl = lane & 15;
    int idx = (fb * NN + wave) * 16 + fl;
    float pf = (Pf[idx] + __half2float(Ah[idx])) * dinv[wave];
    float scale = g[lane] * rsqrtf(rv[lane] + FEPS);
    float shift = be[lane] + (bb[lane] - rm[lane]) * scale;
    float o0 = 0.f, o1 = 0.f, o2 = 0.f, o3 = 0.f;
#pragma unroll
    for (int k2 = 0; k2 < 64; k2 += 4) {
        o0 = fmaf(__shfl(pf, k2 + 0, 64), Ws[(k2 + 0) * 64 + lane], o0);
        o1 = fmaf(__shfl(pf, k2 + 1, 64), Ws[(k2 + 1) * 64 + lane], o1);
        o2 = fmaf(__shfl(pf, k2 + 2, 64), Ws[(k2 + 2) * 64 + lane], o2);
        o3 = fmaf(__shfl(pf, k2 + 3, 64), Ws[(k2 + 3) * 64 + lane], o3);
    }
    float o = (o0 + o1) + (o2 + o3);
    o = fmaxf(fmaf(o, scale, shift), 0.f);
    outRow[wave * 64 + lane] = __float2half(o * dinv[wave]);   // pre-scaled
}

// ---------- layer 3: R5-style row-gather + transform + BN + ReLU + pool -----
__global__ __launch_bounds__(256) void k_gx64p(const __half* __restrict__ Hin,
                                               const int* __restrict__ rowptr,
                                               const int* __restrict__ cnt,
                                               const float* __restrict__ dinv,
                                               const int* __restrict__ csr,
                                               const float* __restrict__ W,
                                               const float* __restrict__ bb,
                                               const float* __restrict__ g,
                                               const float* __restrict__ be,
                                               const float* __restrict__ rm,
                                               const float* __restrict__ rv,
                                               const int* __restrict__ batch,
                                               float* __restrict__ sums) {
    __shared__ float Ws[4096];
    int tid = threadIdx.x;
    for (int i = tid; i < 4096; i += 256) Ws[i] = W[i];
    __syncthreads();
    int wave = (blockIdx.x * 256 + tid) >> 6;
    int lane = tid & 63;
    if (wave >= NN) return;
    int st = rowptr[wave], n = cnt[wave];
    float a0 = __half2float(Hin[wave * 64 + lane]);  // self (pre-scaled)
    float a1 = 0.f;
    int k = 0;
    while (k < n) {
        int rem = n - k;
        int chunk = rem < 64 ? rem : 64;
        int ew = (lane < chunk) ? csr[st + k + lane] : 0;
        int j = 0;
        for (; j + 8 <= chunk; j += 8) {
            int s0 = __shfl(ew, j + 0, 64);
            int s1 = __shfl(ew, j + 1, 64);
            int s2 = __shfl(ew, j + 2, 64);
            int s3 = __shfl(ew, j + 3, 64);
            int s4 = __shfl(ew, j + 4, 64);
            int s5 = __shfl(ew, j + 5, 64);
            int s6 = __shfl(ew, j + 6, 64);
            int s7 = __shfl(ew, j + 7, 64);
            float v0 = __half2float(Hin[s0 * 64 + lane]);
            float v1 = __half2float(Hin[s1 * 64 + lane]);
            float v2 = __half2float(Hin[s2 * 64 + lane]);
            float v3 = __half2float(Hin[s3 * 64 + lane]);
            float v4 = __half2float(Hin[s4 * 64 + lane]);
            float v5 = __half2float(Hin[s5 * 64 + lane]);
            float v6 = __half2float(Hin[s6 * 64 + lane]);
            float v7 = __half2float(Hin[s7 * 64 + lane]);
            a0 += (v0 + v1) + (v2 + v3);
            a1 += (v4 + v5) + (v6 + v7);
        }
        for (; j < chunk; ++j) {
            int s = __shfl(ew, j, 64);
            a0 += __half2float(Hin[s * 64 + lane]);
        }
        k += chunk;
    }
    float pf = (a0 + a1) * dinv[wave];
    float scale = g[lane] * rsqrtf(rv[lane] + FEPS);
    float shift = be[lane] + (bb[lane] - rm[lane]) * scale;
    float o0 = 0.f, o1 = 0.f, o2 = 0.f, o3 = 0.f;
#pragma unroll
    for (int k2 = 0; k2 < 64; k2 += 4) {
        o0 = fmaf(__shfl(pf, k2 + 0, 64), Ws[(k2 + 0) * 64 + lane], o0);
        o1 = fmaf(__shfl(pf, k2 + 1, 64), Ws[(k2 + 1) * 64 + lane], o1);
        o2 = fmaf(__shfl(pf, k2 + 2, 64), Ws[(k2 + 2) * 64 + lane], o2);
        o3 = fmaf(__shfl(pf, k2 + 3, 64), Ws[(k2 + 3) * 64 + lane], o3);
    }
    float o = (o0 + o1) + (o2 + o3);
    o = fmaxf(fmaf(o, scale, shift), 0.f);
    atomicAdd(&sums[batch[wave] * 64 + lane], o);
}

// ---------- head ----------

__global__ __launch_bounds__(256) void k_head(const float* __restrict__ sums,
                                              const float* __restrict__ cnts,
                                              const float* __restrict__ Wr1,
                                              const float* __restrict__ br1,
                                              const float* __restrict__ Wr2,
                                              const float* __restrict__ br2,
                                              float* __restrict__ out) {
    int wave = (blockIdx.x * 256 + threadIdx.x) >> 6;
    int lane = threadIdx.x & 63;
    if (wave >= NG) return;
    float c = fmaxf(cnts[wave], 1.0f);
    float pooled = sums[wave * 64 + lane] / c;
    float acc = 0.f;
#pragma unroll
    for (int k = 0; k < 64; ++k)
        acc = fmaf(__shfl(pooled, k, 64), Wr1[k * 64 + lane], acc);
    float hid = fmaxf(acc + br1[lane], 0.f);
    float o0 = hid * Wr2[lane * 2 + 0];
    float o1 = hid * Wr2[lane * 2 + 1];
#pragma unroll
    for (int off = 32; off > 0; off >>= 1) {
        o0 += __shfl_xor(o0, off, 64);
        o1 += __shfl_xor(o1, off, 64);
    }
    if (lane == 0) {
        out[wave * 2 + 0] = o0 + br2[0];
        out[wave * 2 + 1] = o1 + br2[1];
    }
}

extern "C" void kernel_launch(void* const* d_in, const int* in_sizes, int n_in,
                              void* d_out, int out_size, void* d_ws, size_t ws_size,
                              hipStream_t stream) {
    const float* x   = (const float*)d_in[0];
    const int*   ei  = (const int*)d_in[1];     // [2, E]: row0=src, row1=dst
    const int*   bat = (const int*)d_in[2];
    const float* W1  = (const float*)d_in[3];
    const float* b1  = (const float*)d_in[4];
    const float* g1  = (const float*)d_in[5];
    const float* be1 = (const float*)d_in[6];
    const float* rm1 = (const float*)d_in[7];
    const float* rv1 = (const float*)d_in[8];
    const float* W2  = (const float*)d_in[9];
    const float* b2  = (const float*)d_in[10];
    const float* g2  = (const float*)d_in[11];
    const float* be2 = (const float*)d_in[12];
    const float* rm2 = (const float*)d_in[13];
    const float* rv2 = (const float*)d_in[14];
    const float* W3  = (const float*)d_in[15];
    const float* b3  = (const float*)d_in[16];
    const float* g3  = (const float*)d_in[17];
    const float* be3 = (const float*)d_in[18];
    const float* rm3 = (const float*)d_in[19];
    const float* rv3 = (const float*)d_in[20];
    const float* Wr1 = (const float*)d_in[21];
    const float* br1 = (const float*)d_in[22];
    const float* Wr2 = (const float*)d_in[23];
    const float* br2 = (const float*)d_in[24];
    float* out = (float*)d_out;

    // workspace layout (4-byte words), ~67 MB total (R1 proved ws >= ~90 MB)
    int*    cnt    = (int*)d_ws;               // NN
    int*    rowptr = cnt + NN;                 // NN
    int*    bsum   = rowptr + NN;              // 512
    int*    bh     = bsum + 512;               // NB
    int*    bboff  = bh + NB;                  // NB+1
    int*    bcur   = bboff + NB + 1;           // NB
    float*  dinv   = (float*)(bcur + NB);      // NN
    int*    csr    = (int*)(dinv + NN);        // NE
    __half* xs     = (__half*)(csr + NE);      // NN*8 halves
    float*  sums   = (float*)(xs + NN * 8);    // NG*64
    float*  cnts   = sums + NG * 64;           // NG
    __half* Afb    = (__half*)(cnts + NG);     // NF halves (fb-split layer-1 out)
    __half* B      = Afb + NF;                 // NF halves (row-major layer-2 out)
    float*  P      = (float*)(B + NF);         // NF floats (4 x NN x 16 partials)
    int2*   ebuf   = (int2*)P;                 // NE int2 == NF words; dead after
                                               //  kB_fill, before first k_pass

    const int* srcI = ei;
    const int* dstI = ei + NE;

    const int gA = ceil_div(NE, CHA);        // 391
    const int gN = ceil_div(NN, 256);        // 391
    const int gW = ceil_div(NN * 64, 256);   // 25000 wave-per-node blocks

    hipMemsetAsync(bh, 0, NB * sizeof(int), stream);
    hipMemsetAsync(sums, 0, (NG * 64 + NG) * sizeof(float), stream);

    // CSR build (R6's proven bucketed pipeline, src-only records)
    kA_hist<<<gA, 256, 0, stream>>>(dstI, bh);
    kA_scan<<<1, 512, 0, stream>>>(bh, bboff, bcur);
    kA_fill<<<gA, 256, 0, stream>>>(srcI, dstI, bcur, ebuf);
    kB_hist<<<NB, 256, 0, stream>>>(ebuf, bboff, cnt);
    k_dinv_xs<<<gN, 256, 0, stream>>>(cnt, x, dinv, xs);
    k_cnts<<<ceil_div(ceil_div(NN, 64), 256), 256, 0, stream>>>(bat, cnts);
    k_scan1<<<gN, 256, 0, stream>>>(cnt, bsum);
    k_scan2<<<1, 512, 0, stream>>>(bsum, gN);
    k_scan3<<<gN, 256, 0, stream>>>(cnt, bsum, rowptr);
    kB_fill<<<NB, 256, 0, stream>>>(ebuf, bboff, rowptr, csr);

    // layer 1: gather(xs) + 8->64 + BN + ReLU -> Afb (fb-split, pre-scaled)
    k_gxf8<<<gW, 256, 0, stream>>>((const __half2*)xs, rowptr, cnt, dinv, csr,
                                   W1, b1, g1, be1, rm1, rv1, Afb);

    // layer 2 (A/B arm 1): 4 feature-split L2-resident passes + transform
    for (int fb = 0; fb < 4; ++fb) {
        k_pass<<<gW, 256, 0, stream>>>((const __half2*)(Afb + fb * NN * 16),
                                       rowptr, cnt, csr,
                                       (float2*)(P + fb * NN * 16));
    }
    k_xf2<<<gW, 256, 0, stream>>>(P, Afb, dinv,
                                  W2, b2, g2, be2, rm2, rv2, B);

    // layer 3 (A/B arm 2): best row-gather (R5 form) + pool fusion
    k_gx64p<<<gW, 256, 0, stream>>>(B, rowptr, cnt, dinv, csr,
                                    W3, b3, g3, be3, rm3, rv3, bat, sums);

    k_head<<<ceil_div(NG * 64, 256), 256, 0, stream>>>(sums, cnts, Wr1, br1, Wr2, br2, out);
}